// Round 2
// baseline (225.151 us; speedup 1.0000x reference)
//
#include <hip/hip_runtime.h>

// GAT_gate: B=16, N=1024, D=128. FP32 I/O; bf16 MFMA internally, fp32 accum.
//
// Round-13: round-12's k3 restructure (column-split waves, LDS-staged att)
// FAILED on precision: k2c's hT2 = bf16(bf16(h)*rl0) double-rounds the B
// operand (absmax 0.0127 -> 0.0142, over tolerance). This round keeps the
// new k3 structure but restores r11's exact rounding chain: k2c dropped,
// rl0 applied on the A side in fp32 inside k3's K-loop (av = bf16(b2f(att)
// * rl0)), B = single-rounded bf16 hT. VALU cost of the repack ~770 ops/lane
// (~2.6us device-wide) and overlaps the MFMA pipe.
//
//  K0:    WwB = bf16(Ww); W2T = bf16(A^T Ww); wbA = Wb@A (fp32)
//  kmask: adj (64MB fp32) -> 2MB bitmask
//  K1:    h = x@Ww^T+Wb ; u = x@W2T^T+wbA -> h,u bf16; hT bf16 [b][d][n]
//  K2s:   att = mask?exp(e):0 bf16 (LDS-staged 64B row writes); partial colsums
//  K2b:   rl0[j] = 1 / sum_iblk colpart
//  K3g:   h' = relu((att*rl0) @ hT) + LSTM gates. att block (16x1024 bf16 =
//         32KB) staged via global_load_lds w=16 with pre-swizzled SOURCE
//         (cb ^ ((row&7)<<4)); waves own 2 d-tiles, full K=1024 each.

#define B_ 16
#define N_ 1024
#define D_ 128

typedef __attribute__((ext_vector_type(8))) short bf16x8;
typedef __attribute__((ext_vector_type(4))) float f32x4;

__device__ __forceinline__ float b2f(unsigned short u) {
    union { unsigned int i; float f; } v; v.i = ((unsigned int)u) << 16; return v.f;
}
__device__ __forceinline__ unsigned short f2b(float f) {
    union { float f; unsigned int i; } v; v.f = f;
    unsigned int x = v.i;
    return (unsigned short)((x + 0x7fffu + ((x >> 16) & 1u)) >> 16);
}
__device__ __forceinline__ float clamp60(float v) {
    return fminf(fmaxf(v, -60.f), 60.f);
}
__device__ __forceinline__ bf16x8 load8f(const float* p) {
    float4 a = *reinterpret_cast<const float4*>(p);
    float4 b = *reinterpret_cast<const float4*>(p + 4);
    bf16x8 v;
    v[0] = (short)f2b(a.x); v[1] = (short)f2b(a.y);
    v[2] = (short)f2b(a.z); v[3] = (short)f2b(a.w);
    v[4] = (short)f2b(b.x); v[5] = (short)f2b(b.y);
    v[6] = (short)f2b(b.z); v[7] = (short)f2b(b.w);
    return v;
}

// ---------------- K0: fold weights ----------------
__global__ __launch_bounds__(256) void k0_w2t(
    const float* __restrict__ Ww, const float* __restrict__ Wb,
    const float* __restrict__ A, unsigned short* __restrict__ WwB,
    unsigned short* __restrict__ W2T, float* __restrict__ wbA) {
    int t = blockIdx.x * 256 + threadIdx.x;
    int l = t >> 7, f = t & 127;
    float acc = 0.f;
    for (int d = 0; d < 128; ++d)
        acc += A[d * 128 + l] * Ww[d * 128 + f];
    W2T[l * 128 + f] = f2b(acc);
    WwB[t] = f2b(Ww[t]);
    if (blockIdx.x == 0 && threadIdx.x < 128) {
        float s = 0.f;
        for (int d = 0; d < 128; ++d) s += Wb[d] * A[d * 128 + threadIdx.x];
        wbA[threadIdx.x] = s;
    }
}

// ---------------- kmask: adj -> bitmask ----------------
__global__ __launch_bounds__(256) void kmask(
    const float* __restrict__ adj, unsigned long long* __restrict__ maskJ) {
    int w = threadIdx.x >> 6, lane = threadIdx.x & 63;
    size_t base = ((size_t)blockIdx.x * 4 + w) * 256;
    unsigned long long w0 = __ballot(adj[base + 0 * 64 + lane] > 0.f);
    unsigned long long w1 = __ballot(adj[base + 1 * 64 + lane] > 0.f);
    unsigned long long w2 = __ballot(adj[base + 2 * 64 + lane] > 0.f);
    unsigned long long w3 = __ballot(adj[base + 3 * 64 + lane] > 0.f);
    unsigned long long o = lane == 0 ? w0 : lane == 1 ? w1 : lane == 2 ? w2 : w3;
    if (lane < 4) maskJ[(base >> 6) + lane] = o;
}

// ---------------- K1: h, u, hT ----------------
__global__ __launch_bounds__(256) void k1_hu(
    const float* __restrict__ x, const unsigned short* __restrict__ WwB,
    const float* __restrict__ Wb, const unsigned short* __restrict__ W2T,
    const float* __restrict__ wbA,
    unsigned short* __restrict__ h, unsigned short* __restrict__ u,
    unsigned short* __restrict__ hT) {
    __shared__ unsigned short lds[16][128];
    int w = threadIdx.x >> 6, lane = threadIdx.x & 63;
    int c = lane & 15, q = lane >> 4;
    int rowbase = blockIdx.x * 16;
    int b = rowbase >> 10;
    int n0 = rowbase & 1023;
    bf16x8 xa[4];
    const float* xrow = x + (size_t)(rowbase + c) * 128;
#pragma unroll
    for (int ks = 0; ks < 4; ++ks)
        xa[ks] = load8f(xrow + ks * 32 + q * 8);
#pragma unroll
    for (int tt = 0; tt < 2; ++tt) {
        int t = w * 2 + tt;
        f32x4 acch = {0.f, 0.f, 0.f, 0.f};
        f32x4 accu = {0.f, 0.f, 0.f, 0.f};
        const unsigned short* wwrow = WwB + (t * 16 + c) * 128;
        const unsigned short* w2row = W2T + (t * 16 + c) * 128;
#pragma unroll
        for (int ks = 0; ks < 4; ++ks) {
            bf16x8 bw = *reinterpret_cast<const bf16x8*>(wwrow + ks * 32 + q * 8);
            bf16x8 b2 = *reinterpret_cast<const bf16x8*>(w2row + ks * 32 + q * 8);
            acch = __builtin_amdgcn_mfma_f32_16x16x32_bf16(xa[ks], bw, acch, 0, 0, 0);
            accu = __builtin_amdgcn_mfma_f32_16x16x32_bf16(xa[ks], b2, accu, 0, 0, 0);
        }
        float wb = Wb[t * 16 + c];
        float ub = wbA[t * 16 + c];
#pragma unroll
        for (int r = 0; r < 4; ++r) {
            int row = rowbase + q * 4 + r;
            unsigned short hv = f2b(acch[r] + wb);
            unsigned short uv = f2b(accu[r] + ub);
            h[(size_t)row * 128 + t * 16 + c] = hv;
            u[(size_t)row * 128 + t * 16 + c] = uv;
            lds[q * 4 + r][t * 16 + c] = hv;
        }
    }
    __syncthreads();
    int tid = threadIdx.x;
    if (tid < 128) {
        int d = tid;
        unsigned int p[8];
#pragma unroll
        for (int k = 0; k < 8; ++k) {
            unsigned int v0 = lds[2 * k][d], v1 = lds[2 * k + 1][d];
            p[k] = v0 | (v1 << 16);
        }
        size_t basehT = ((size_t)(b * 128 + d)) * 1024 + n0;
        uint4* dst = reinterpret_cast<uint4*>(hT + basehT);
        dst[0] = make_uint4(p[0], p[1], p[2], p[3]);
        dst[1] = make_uint4(p[4], p[5], p[6], p[7]);
    }
}

// K2s: grid 512: block = 32 rows i, all 1024 j; j-tile PAIRS; 8 MFMA chains;
// att writes staged in LDS -> 64B fully-covered row segments.
__global__ __launch_bounds__(256) void k2_scores(
    const unsigned short* __restrict__ h, const unsigned short* __restrict__ u,
    const unsigned long long* __restrict__ maskJ,
    unsigned short* __restrict__ att, float* __restrict__ colpart) {
    __shared__ unsigned long long lmask[32][16];
    __shared__ __align__(16) unsigned short stage[4][32][40];  // +8 pad vs 32
    int w = threadIdx.x >> 6, lane = threadIdx.x & 63;
    int c = lane & 15, q = lane >> 4;
    int b = blockIdx.x >> 5;
    int iblk = blockIdx.x & 31;
    int i0 = iblk * 32;
    const unsigned short* hb = h + (size_t)b * N_ * D_;
    const unsigned short* ub = u + (size_t)b * N_ * D_;

    {
        int tid = threadIdx.x;
        lmask[tid >> 4][tid & 15] =
            maskJ[(size_t)(b * 1024 + i0 + (tid >> 4)) * 16 + (tid & 15)];
        lmask[16 + (tid >> 4)][tid & 15] =
            maskJ[(size_t)(b * 1024 + i0 + 16 + (tid >> 4)) * 16 + (tid & 15)];
    }
    __syncthreads();

    bf16x8 Au0[4], Ah0[4], Au1[4], Ah1[4];
#pragma unroll
    for (int ks = 0; ks < 4; ++ks) {
        Au0[ks] = *reinterpret_cast<const bf16x8*>(ub + (i0 + c) * 128 + ks * 32 + q * 8);
        Ah0[ks] = *reinterpret_cast<const bf16x8*>(hb + (i0 + c) * 128 + ks * 32 + q * 8);
        Au1[ks] = *reinterpret_cast<const bf16x8*>(ub + (i0 + 16 + c) * 128 + ks * 32 + q * 8);
        Ah1[ks] = *reinterpret_cast<const bf16x8*>(hb + (i0 + 16 + c) * 128 + ks * 32 + q * 8);
    }
    unsigned short* attrow = att + ((size_t)(b * 1024 + i0)) * 1024;
    float* cprow = colpart + ((size_t)(b * 32 + iblk)) * 1024;

    int jt0 = w * 16;                     // wave w owns tiles jt0..jt0+15
#pragma unroll
    for (int p = 0; p < 8; ++p) {
        int jt = jt0 + p * 2;             // pair (jt, jt+1)
        int j0 = jt * 16;
        bf16x8 Bh[2][4], Bu[2][4];
#pragma unroll
        for (int s = 0; s < 2; ++s)
#pragma unroll
            for (int ks = 0; ks < 4; ++ks) {
                Bh[s][ks] = *reinterpret_cast<const bf16x8*>(
                    hb + (j0 + s * 16 + c) * 128 + ks * 32 + q * 8);
                Bu[s][ks] = *reinterpret_cast<const bf16x8*>(
                    ub + (j0 + s * 16 + c) * 128 + ks * 32 + q * 8);
            }
        f32x4 acc[2][2][2];               // [rowgrp g][jhalf s][prod]
#pragma unroll
        for (int g = 0; g < 2; ++g)
#pragma unroll
            for (int s = 0; s < 2; ++s)
#pragma unroll
                for (int pr = 0; pr < 2; ++pr)
                    acc[g][s][pr] = (f32x4){0.f, 0.f, 0.f, 0.f};
#pragma unroll
        for (int ks = 0; ks < 4; ++ks) {
            acc[0][0][0] = __builtin_amdgcn_mfma_f32_16x16x32_bf16(Au0[ks], Bh[0][ks], acc[0][0][0], 0, 0, 0);
            acc[0][0][1] = __builtin_amdgcn_mfma_f32_16x16x32_bf16(Ah0[ks], Bu[0][ks], acc[0][0][1], 0, 0, 0);
            acc[1][0][0] = __builtin_amdgcn_mfma_f32_16x16x32_bf16(Au1[ks], Bh[0][ks], acc[1][0][0], 0, 0, 0);
            acc[1][0][1] = __builtin_amdgcn_mfma_f32_16x16x32_bf16(Ah1[ks], Bu[0][ks], acc[1][0][1], 0, 0, 0);
            acc[0][1][0] = __builtin_amdgcn_mfma_f32_16x16x32_bf16(Au0[ks], Bh[1][ks], acc[0][1][0], 0, 0, 0);
            acc[0][1][1] = __builtin_amdgcn_mfma_f32_16x16x32_bf16(Ah0[ks], Bu[1][ks], acc[0][1][1], 0, 0, 0);
            acc[1][1][0] = __builtin_amdgcn_mfma_f32_16x16x32_bf16(Au1[ks], Bh[1][ks], acc[1][1][0], 0, 0, 0);
            acc[1][1][1] = __builtin_amdgcn_mfma_f32_16x16x32_bf16(Ah1[ks], Bu[1][ks], acc[1][1][1], 0, 0, 0);
        }
        float colpA = 0.f, colpB = 0.f;
#pragma unroll
        for (int s = 0; s < 2; ++s) {
            int jts = jt + s;
            int wd = jts >> 2, sh = (jts & 3) * 16;
#pragma unroll
            for (int g = 0; g < 2; ++g)
#pragma unroll
                for (int r = 0; r < 4; ++r) {
                    float e = acc[g][s][0][r] + acc[g][s][1][r];
                    int row = g * 16 + q * 4 + r;
                    bool m = (lmask[row][wd] >> (sh + c)) & 1ull;
                    float ex = m ? __expf(clamp60(e)) : 0.f;
                    float cadd = m ? ex : 1.0f;
                    if (s == 0) colpA += cadd; else colpB += cadd;
                    stage[w][row][s * 16 + c] = f2b(ex);
                }
        }
        colpA += __shfl_xor(colpA, 16, 64);
        colpA += __shfl_xor(colpA, 32, 64);
        colpB += __shfl_xor(colpB, 16, 64);
        colpB += __shfl_xor(colpB, 32, 64);
        if (q == 0) {
            cprow[j0 + c] = colpA;
            cprow[j0 + 16 + c] = colpB;
        }
        // write out 32 rows x 64B, fully covered (wave-internal LDS roundtrip)
        int row2 = lane & 31, half = lane >> 5;
        const uint4* sp = reinterpret_cast<const uint4*>(&stage[w][row2][half * 16]);
        uint4 v0 = sp[0], v1 = sp[1];
        uint4* gp = reinterpret_cast<uint4*>(attrow + (size_t)row2 * 1024 + j0 + half * 16);
        gp[0] = v0; gp[1] = v1;
    }
}

// K2b: rl0 = 1/sum(colpart)
__global__ __launch_bounds__(256) void k2b_recip(
    const float* __restrict__ colpart, float* __restrict__ rl0) {
    int g = blockIdx.x * 256 + threadIdx.x;
    int b = g >> 10, j = g & 1023;
    float s = 0.f;
    const float* p = colpart + (size_t)b * 32 * 1024 + j;
    for (int ib = 0; ib < 32; ++ib) s += p[(size_t)ib * 1024];
    rl0[g] = 1.0f / s;
}

// K3g: h' = relu((att*rl0) @ hT) + gates. Waves split over OUTPUT d-tiles
// (full K per wave). att 16x1024 block staged in LDS (swizzled src). rl0
// applied on the A side in fp32 (r11 rounding chain: bf16(b2f(att)*rl0)).
__global__ __launch_bounds__(256) void k3_gemm(
    const unsigned short* __restrict__ att, const float* __restrict__ rl0,
    const unsigned short* __restrict__ hT, const float* __restrict__ x,
    const float* __restrict__ wi_u, const float* __restrict__ wi_x,
    const float* __restrict__ wf_u, const float* __restrict__ wf_x,
    const float* __restrict__ wo_u, const float* __restrict__ wo_x,
    float* __restrict__ out) {
    // 32KB exactly: att stage during K-loop; gate partials overlay afterwards.
    __shared__ __align__(16) unsigned short smem[16384];
    int w = threadIdx.x >> 6, lane = threadIdx.x & 63;
    int c = lane & 15, q = lane >> 4;
    int b = blockIdx.x >> 6;
    int i0 = (blockIdx.x & 63) * 16;

    // ---- cooperative swizzled stage: LDS[row][cb] = att[i0+row][cb ^ ((row&7)<<4)]
    // att block = 16 rows x 2048B, fully contiguous in global.
    const char* attblk = reinterpret_cast<const char*>(att + ((size_t)(b * 1024 + i0)) * 1024);
#pragma unroll
    for (int it = 0; it < 8; ++it) {
        int L = it * 4096 + w * 1024;            // wave-uniform LDS byte base
        int row = L >> 11;                       // uniform per wave
        int swz = (row & 7) << 4;
        int cb = (L & 2047) + lane * 16;         // per-lane col-byte (pre-swz)
        const char* src = attblk + (row << 11) + (cb ^ swz);
        unsigned short* dst = smem + (L >> 1);   // wave-uniform; lane*16 implicit
        __builtin_amdgcn_global_load_lds(
            (const __attribute__((address_space(1))) unsigned int*)(const void*)src,
            (__attribute__((address_space(3))) unsigned int*)(void*)dst, 16, 0, 0);
    }
    __syncthreads();  // compiler drains vmcnt(0) before s_barrier

    // ---- K-loop: wave w owns d-tiles t0=2w, t1=2w+1; full K=1024.
    int t0 = w * 2, t1 = t0 + 1;
    const unsigned short* hTb = hT + (size_t)b * 128 * 1024;
    const unsigned short* bt0p = hTb + (size_t)(t0 * 16 + c) * 1024 + q * 8;
    const unsigned short* bt1p = hTb + (size_t)(t1 * 16 + c) * 1024 + q * 8;
    const float* rl0p = rl0 + b * 1024 + q * 8;
    const char* avbase = reinterpret_cast<const char*>(smem) + c * 2048;
    int swzc = (c & 7) << 4;
    int offq = q * 16;

    f32x4 acc0 = {0.f, 0.f, 0.f, 0.f};
    f32x4 acc1 = {0.f, 0.f, 0.f, 0.f};
#pragma unroll 4
    for (int jp = 0; jp < 32; ++jp) {
        bf16x8 eraw = *reinterpret_cast<const bf16x8*>(
            avbase + (((jp << 6) + offq) ^ swzc));
        float4 r0 = *reinterpret_cast<const float4*>(rl0p + jp * 32);
        float4 r1 = *reinterpret_cast<const float4*>(rl0p + jp * 32 + 4);
        bf16x8 av;
        av[0] = (short)f2b(b2f((unsigned short)eraw[0]) * r0.x);
        av[1] = (short)f2b(b2f((unsigned short)eraw[1]) * r0.y);
        av[2] = (short)f2b(b2f((unsigned short)eraw[2]) * r0.z);
        av[3] = (short)f2b(b2f((unsigned short)eraw[3]) * r0.w);
        av[4] = (short)f2b(b2f((unsigned short)eraw[4]) * r1.x);
        av[5] = (short)f2b(b2f((unsigned short)eraw[5]) * r1.y);
        av[6] = (short)f2b(b2f((unsigned short)eraw[6]) * r1.z);
        av[7] = (short)f2b(b2f((unsigned short)eraw[7]) * r1.w);
        bf16x8 b0 = *reinterpret_cast<const bf16x8*>(bt0p + jp * 32);
        bf16x8 b1 = *reinterpret_cast<const bf16x8*>(bt1p + jp * 32);
        acc0 = __builtin_amdgcn_mfma_f32_16x16x32_bf16(av, b0, acc0, 0, 0, 0);
        acc1 = __builtin_amdgcn_mfma_f32_16x16x32_bf16(av, b1, acc1, 0, 0, 0);
    }

    // ---- epilogue: relu, per-wave gate partials (32 of 128 d), tiny LDS reduce
    float hp[2][4], xv[2][4];
    const float* xb = x + ((size_t)(b * 1024 + i0)) * 128;
#pragma unroll
    for (int r = 0; r < 4; ++r) {
        hp[0][r] = fmaxf(acc0[r], 0.f);
        hp[1][r] = fmaxf(acc1[r], 0.f);
        xv[0][r] = xb[(size_t)(q * 4 + r) * 128 + t0 * 16 + c];
        xv[1][r] = xb[(size_t)(q * 4 + r) * 128 + t1 * 16 + c];
    }
    float wiu[2], wix[2], wfu[2], wfx[2], wou[2], wox[2];
#pragma unroll
    for (int tt = 0; tt < 2; ++tt) {
        int d = (t0 + tt) * 16 + c;
        wiu[tt] = wi_u[d]; wix[tt] = wi_x[d];
        wfu[tt] = wf_u[d]; wfx[tt] = wf_x[d];
        wou[tt] = wo_u[d]; wox[tt] = wo_x[d];
    }
    float zi[4], zf[4], zo[4];
#pragma unroll
    for (int r = 0; r < 4; ++r) {
        zi[r] = hp[0][r] * wiu[0] + hp[1][r] * wiu[1]
              + xv[0][r] * wix[0] + xv[1][r] * wix[1];
        zf[r] = hp[0][r] * wfu[0] + hp[1][r] * wfu[1]
              + xv[0][r] * wfx[0] + xv[1][r] * wfx[1];
        zo[r] = hp[0][r] * wou[0] + hp[1][r] * wou[1]
              + xv[0][r] * wox[0] + xv[1][r] * wox[1];
        zi[r] += __shfl_xor(zi[r], 1, 64); zi[r] += __shfl_xor(zi[r], 2, 64);
        zi[r] += __shfl_xor(zi[r], 4, 64); zi[r] += __shfl_xor(zi[r], 8, 64);
        zf[r] += __shfl_xor(zf[r], 1, 64); zf[r] += __shfl_xor(zf[r], 2, 64);
        zf[r] += __shfl_xor(zf[r], 4, 64); zf[r] += __shfl_xor(zf[r], 8, 64);
        zo[r] += __shfl_xor(zo[r], 1, 64); zo[r] += __shfl_xor(zo[r], 2, 64);
        zo[r] += __shfl_xor(zo[r], 4, 64); zo[r] += __shfl_xor(zo[r], 8, 64);
    }
    __syncthreads();  // all waves done reading att stage; reuse smem
    float* gp = reinterpret_cast<float*>(smem);  // [4 waves][16 rows][4]
    if (c == 0) {
#pragma unroll
        for (int r = 0; r < 4; ++r) {
            int row = q * 4 + r;
            gp[(w * 16 + row) * 4 + 0] = zi[r];
            gp[(w * 16 + row) * 4 + 1] = zf[r];
            gp[(w * 16 + row) * 4 + 2] = zo[r];
        }
    }
    __syncthreads();
#pragma unroll
    for (int r = 0; r < 4; ++r) {
        int row = q * 4 + r;
        float Zi = gp[(0 * 16 + row) * 4 + 0] + gp[(1 * 16 + row) * 4 + 0]
                 + gp[(2 * 16 + row) * 4 + 0] + gp[(3 * 16 + row) * 4 + 0];
        float Zf = gp[(0 * 16 + row) * 4 + 1] + gp[(1 * 16 + row) * 4 + 1]
                 + gp[(2 * 16 + row) * 4 + 1] + gp[(3 * 16 + row) * 4 + 1];
        float Zo = gp[(0 * 16 + row) * 4 + 2] + gp[(1 * 16 + row) * 4 + 2]
                 + gp[(2 * 16 + row) * 4 + 2] + gp[(3 * 16 + row) * 4 + 2];
        float ic = 1.f / (1.f + __expf(-Zi));
        float fc = 1.f / (1.f + __expf(-Zf));
        float oc = 1.f / (1.f + __expf(-Zo));
#pragma unroll
        for (int tt = 0; tt < 2; ++tt) {
            float zz = ic * hp[tt][r] + fc * xv[tt][r];
            float th = 1.f - 2.f / (__expf(2.f * zz) + 1.f);
            out[(size_t)(b * 1024 + i0 + row) * 128 + (t0 + tt) * 16 + c] = oc * th;
        }
    }
}

extern "C" void kernel_launch(void* const* d_in, const int* in_sizes, int n_in,
                              void* d_out, int out_size, void* d_ws, size_t ws_size,
                              hipStream_t stream) {
    const float* x    = (const float*)d_in[0];
    const float* adj  = (const float*)d_in[1];
    const float* Ww   = (const float*)d_in[2];
    const float* Wb   = (const float*)d_in[3];
    const float* A    = (const float*)d_in[4];
    const float* wi_u = (const float*)d_in[5];
    const float* wi_x = (const float*)d_in[6];
    const float* wf_u = (const float*)d_in[7];
    const float* wf_x = (const float*)d_in[8];
    const float* wo_u = (const float*)d_in[9];
    const float* wo_x = (const float*)d_in[10];
    float* out = (float*)d_out;
    char* ws = (char*)d_ws;

    if (ws_size >= (56ull << 20)) {
        unsigned short* WwB = (unsigned short*)(ws);                      // 32K
        unsigned short* W2T = (unsigned short*)(ws + (32u << 10));        // 32K
        float* wbA          = (float*)(ws + (64u << 10));                 // 512B
        float* rl0          = (float*)(ws + (128u << 10));                // 64K
        unsigned long long* maskJ = (unsigned long long*)(ws + (256u << 10)); // 2M
        float* colpart      = (float*)(ws + (4ull << 20));                // 2M
        unsigned short* h   = (unsigned short*)(ws + (8ull << 20));       // 4M
        unsigned short* u   = (unsigned short*)(ws + (12ull << 20));      // 4M
        unsigned short* hT  = (unsigned short*)(ws + (16ull << 20));      // 4M
        unsigned short* att = (unsigned short*)(ws + (20ull << 20));      // 32M

        k0_w2t<<<64, 256, 0, stream>>>(Ww, Wb, A, WwB, W2T, wbA);
        kmask<<<16384, 256, 0, stream>>>(adj, maskJ);
        k1_hu<<<1024, 256, 0, stream>>>(x, WwB, Wb, W2T, wbA, h, u, hT);
        k2_scores<<<512, 256, 0, stream>>>(h, u, maskJ, att, colpart);
        k2b_recip<<<64, 256, 0, stream>>>(colpart, rl0);
        k3_gemm<<<1024, 256, 0, stream>>>(att, rl0, hT, x,
                                          wi_u, wi_x, wf_u, wf_x, wo_u, wo_x, out);
    } else {
        // tighter layout (~49MB): same kernels
        unsigned short* WwB = (unsigned short*)(ws);
        unsigned short* W2T = (unsigned short*)(ws + (32u << 10));
        float* wbA          = (float*)(ws + (64u << 10));
        float* rl0          = (float*)(ws + (128u << 10));
        unsigned long long* maskJ = (unsigned long long*)(ws + (256u << 10));
        float* colpart      = (float*)(ws + (3ull << 20));
        unsigned short* h   = (unsigned short*)(ws + (5ull << 20));
        unsigned short* u   = (unsigned short*)(ws + (9ull << 20));
        unsigned short* hT  = (unsigned short*)(ws + (13ull << 20));
        unsigned short* att = (unsigned short*)(ws + (17ull << 20));

        k0_w2t<<<64, 256, 0, stream>>>(Ww, Wb, A, WwB, W2T, wbA);
        kmask<<<16384, 256, 0, stream>>>(adj, maskJ);
        k1_hu<<<1024, 256, 0, stream>>>(x, WwB, Wb, W2T, wbA, h, u, hT);
        k2_scores<<<512, 256, 0, stream>>>(h, u, maskJ, att, colpart);
        k2b_recip<<<64, 256, 0, stream>>>(colpart, rl0);
        k3_gemm<<<1024, 256, 0, stream>>>(att, rl0, hT, x,
                                          wi_u, wi_x, wf_u, wf_x, wo_u, wo_x, out);
    }
}